// Round 5
// baseline (406.323 us; speedup 1.0000x reference)
//
#include <hip/hip_runtime.h>
#include <math.h>
#include <stdint.h>

#define B_ 8
#define T_ 128
#define U1_ 33
#define D_ 512
#define V_ 4096
#define M_ (B_*T_*U1_)   /* 33792 */

#define BLANK_ 0
#define PAD_ 1

#define TM 64            /* rows per block (A-resident) */
#define TNH 2048         /* cols per block = V/2 */
#define CH 128           /* chunk cols */
#define NCH (TNH/CH)     /* 16 chunks */
#define BKB 128          /* K per MFMA step (fp8 bytes = elements) */

/* E8M0 block scales: A x1 (bias 127); B x2^-6 (121) undoes the x64 pre-scale */
#define SCALE_A 0x7F7F7F7Fu
#define SCALE_B 0x79797979u

typedef __attribute__((ext_vector_type(4))) float fvec4;
typedef __attribute__((ext_vector_type(8))) int   i8v;    // 32 fp8 = 8 VGPRs
typedef __attribute__((ext_vector_type(4))) int   i4v;

__device__ __forceinline__ void load_lds16(const uint8_t* g, uint8_t* l) {
    __builtin_amdgcn_global_load_lds(
        (const __attribute__((address_space(1))) unsigned int*)g,
        (__attribute__((address_space(3))) unsigned int*)l, 16, 0, 0);
}

__device__ __forceinline__ unsigned pack4_fp8(fvec4 v) {
    int r = __builtin_amdgcn_cvt_pk_fp8_f32(v.x, v.y, 0, false);
    r = __builtin_amdgcn_cvt_pk_fp8_f32(v.z, v.w, r, true);
    return (unsigned)r;
}

// ---------------------------------------------------------------------------
// Kernel A: convert W fp32 -> fp8 (x64 pre-scale); thread 0 zeroes out[0]
// ---------------------------------------------------------------------------
__global__ void wconvert(const float* __restrict__ w, uint8_t* __restrict__ wf8,
                         float* __restrict__ out)
{
    int i = blockIdx.x * 256 + threadIdx.x;
    if (i == 0) out[0] = 0.0f;
    const int nw = (V_ * D_) / 16;   // 131072 groups of 16 elems
    for (int j = i; j < nw; j += gridDim.x * 256) {
        const fvec4* p = (const fvec4*)w + (size_t)j * 4;
        fvec4 v0 = p[0]*64.0f, v1 = p[1]*64.0f, v2 = p[2]*64.0f, v3 = p[3]*64.0f;
        uint4 o = { pack4_fp8(v0), pack4_fp8(v1), pack4_fp8(v2), pack4_fp8(v3) };
        ((uint4*)wf8)[j] = o;
    }
}

// ---------------------------------------------------------------------------
// Kernel B: A-resident strip GEMM. Block = 64 rows x 2048 cols (half of V).
// A fragments converted fp32->fp8 inline, held in registers for all 16 chunks.
// B double-buffered via global_load_lds (XOR chunk swizzle). se/sz accumulate
// in registers; cross-wave combine via LDS atomics ONCE per block (R4 bug:
// two waves share each row — a direct write raced/overwrote; must add).
// grid (528, 2), block 256 = 2x2 waves, wave tile 32x64.
// ---------------------------------------------------------------------------
__global__ __launch_bounds__(256, 2)
void gemm_fused(const float* __restrict__ x, const uint8_t* __restrict__ wf8,
                const float* __restrict__ bias, const int* __restrict__ targets,
                float* __restrict__ partial_e, float* __restrict__ partial_z,
                float* __restrict__ blank_z, float* __restrict__ emit_z)
{
    __shared__ __align__(16) uint8_t Bs[2][CH * BKB];   // 16 KB x2
    __shared__ float ps[TM], pz[TM];
    __shared__ int tgt_s[TM];

    const int tid  = threadIdx.x;
    const int lane = tid & 63;
    const int wid  = tid >> 6;
    const int m0   = blockIdx.x * TM;
    const int half = blockIdx.y;
    const int n0   = half * TNH;

    const int wrow = (wid >> 1) * 32;
    const int wcol = (wid & 1) * 64;
    const int m15  = lane & 15;
    const int quad = lane >> 4;

    // B staging map: lane -> (row within chunk, 16B k-chunk), XOR swizzled
    const int srow = wid * 32 + (lane >> 3);
    const int schk = (lane & 7) ^ ((lane >> 3) & 7);
    const uint8_t* bgp = wf8 + (size_t)(n0 + srow) * D_ + schk * 16;

    auto stageB = [&](int buf, int st) {
        const int chunk = st >> 2, ks = st & 3;
        const uint8_t* bg = bgp + (size_t)chunk * CH * D_ + ks * BKB;
#pragma unroll
        for (int j = 0; j < 4; j++)
            load_lds16(bg + j * 8 * D_, &Bs[buf][(wid * 32 + j * 8) * BKB]);
    };

    if (tid < TM) {
        int row = m0 + tid, u = row % U1_, b = row / (T_ * U1_);
        tgt_s[tid] = (u < U1_ - 1) ? targets[b * (U1_ - 1) + u] : -1;
        ps[tid] = 0.0f; pz[tid] = 0.0f;
    }

    // A fragments: rows wrow+mi*16+m15, k elems = ks*128 + quad*32 .. +32
    i8v afrag[2][4];
#pragma unroll
    for (int mi = 0; mi < 2; mi++) {
        const float* xr = x + (size_t)(m0 + wrow + mi * 16 + m15) * D_ + quad * 32;
#pragma unroll
        for (int ks = 0; ks < 4; ks++) {
            union { unsigned u[8]; i8v v; } pk;
#pragma unroll
            for (int j = 0; j < 8; j++)
                pk.u[j] = pack4_fp8(*(const fvec4*)(xr + ks * 128 + j * 4));
            afrag[mi][ks] = pk.v;
        }
    }

    fvec4 acc[2][4];
    float se_reg[2][4], sz_reg[2][4];
#pragma unroll
    for (int mi = 0; mi < 2; mi++)
#pragma unroll
        for (int j = 0; j < 4; j++) {
            acc[mi][j] = (fvec4)0.0f;
            se_reg[mi][j] = 0.0f; sz_reg[mi][j] = 0.0f;
        }

    stageB(0, 0);
    __syncthreads();

    const int e   = m15 & 7;
    const int c0b = (((quad << 1) ^ e) << 4);

    for (int chunk = 0; chunk < NCH; chunk++) {
        float bv[4];
#pragma unroll
        for (int ni = 0; ni < 4; ni++)
            bv[ni] = bias[n0 + chunk * CH + wcol + ni * 16 + m15];

#pragma unroll
        for (int ks = 0; ks < 4; ks++) {
            const int cur = ks & 1;          // chunk*4 is even
            const int ns = chunk * 4 + ks + 1;
            if (ns < NCH * 4) stageB(cur ^ 1, ns);

            i8v fb[4];
#pragma unroll
            for (int ni = 0; ni < 4; ni++) {
                const int base = (wcol + ni * 16 + m15) * BKB;
                union { i4v h[2]; i8v w; } u;
                u.h[0] = *(const i4v*)&Bs[cur][base + c0b];
                u.h[1] = *(const i4v*)&Bs[cur][base + (c0b ^ 16)];
                fb[ni] = u.w;
            }
#pragma unroll
            for (int mi = 0; mi < 2; mi++)
#pragma unroll
                for (int ni = 0; ni < 4; ni++)
                    acc[mi][ni] = __builtin_amdgcn_mfma_scale_f32_16x16x128_f8f6f4(
                                      afrag[mi][ks], fb[ni], acc[mi][ni],
                                      0, 0, 0, SCALE_A, 0, SCALE_B);
            __syncthreads();
        }

        // chunk epilogue: accumulate se/sz in regs; extract blank/target logits
        const int cb = n0 + chunk * CH + wcol + m15;
        const bool bl = (half == 0) && (chunk == 0) && (wcol == 0) && (m15 == 0);
#pragma unroll
        for (int mi = 0; mi < 2; mi++) {
#pragma unroll
            for (int r = 0; r < 4; r++) {
                const int lrow = wrow + mi * 16 + quad * 4 + r;
                const int trg = tgt_s[lrow];
#pragma unroll
                for (int ni = 0; ni < 4; ni++) {
                    float z = acc[mi][ni][r] + bv[ni];
                    se_reg[mi][r] += __expf(z);
                    sz_reg[mi][r] += z;
                    if (trg == cb + ni * 16) emit_z[m0 + lrow] = z;
                }
                if (bl) blank_z[m0 + lrow] = acc[mi][0][r] + bv[0];
            }
        }
#pragma unroll
        for (int mi = 0; mi < 2; mi++)
#pragma unroll
            for (int ni = 0; ni < 4; ni++) acc[mi][ni] = (fvec4)0.0f;
    }

    // final: 16-lane shfl reduce, then cross-wave LDS atomic combine (2 waves
    // share each row), then one global write per row.
#pragma unroll
    for (int mi = 0; mi < 2; mi++)
#pragma unroll
        for (int r = 0; r < 4; r++) {
            float se = se_reg[mi][r], sz = sz_reg[mi][r];
#pragma unroll
            for (int off = 1; off < 16; off <<= 1) {
                se += __shfl_xor(se, off, 64);
                sz += __shfl_xor(sz, off, 64);
            }
            if (m15 == 0) {
                int lrow = wrow + mi * 16 + quad * 4 + r;
                atomicAdd(&ps[lrow], se);
                atomicAdd(&pz[lrow], sz);
            }
        }
    __syncthreads();
    if (tid < TM) {
        partial_e[(size_t)half * M_ + m0 + tid] = ps[tid];
        partial_z[(size_t)half * M_ + m0 + tid] = pz[tid];
    }
}

// ---------------------------------------------------------------------------
// Kernel C: fused combine (lse) + label-smoothed CE + RNN-T DP. 1 block / b.
// ---------------------------------------------------------------------------
__global__ __launch_bounds__(256)
void dp_kernel(const float* __restrict__ pe, const float* __restrict__ pz,
               const float* __restrict__ blank_z, const float* __restrict__ emit_z,
               const int* __restrict__ targets, const int* __restrict__ src_lengths,
               const int* __restrict__ tgt_lengths, float* __restrict__ out)
{
    __shared__ float blp[T_ * U1_];
    __shared__ float elp[T_ * U1_];
    const int tid = threadIdx.x;
    const int b = blockIdx.x;
    const int base = b * T_ * U1_;

    for (int i = tid; i < T_ * U1_; i += 256) {
        int g = base + i;
        float l = __logf(pe[g] + pe[M_ + g]);
        blp[i] = blank_z[g] - l;
        elp[i] = emit_z[g] - l;
    }
    __syncthreads();

    const int sl = src_lengths[b], tl = tgt_lengths[b];

    // CE at t = sl-1 (wave 0, lanes 0..31)
    if (tid < 32) {
        int u = tid;
        int tgt = targets[b * (U1_ - 1) + u];
        float contrib = 0.0f;
        int g = base + (sl - 1) * U1_ + u;
        if (tgt != PAD_) {
            float l = __logf(pe[g] + pe[M_ + g]);
            float sz = pz[g] + pz[M_ + g];
            float nll = l - emit_z[g];
            float smooth = (float)V_ * l - sz;
            const float eps_i = 0.1f / (float)(V_ - 1);
            contrib = (1.0f - 0.1f - eps_i) * nll + eps_i * smooth;
        }
#pragma unroll
        for (int off = 1; off < 32; off <<= 1) contrib += __shfl_xor(contrib, off, 32);
        if (u == 0) atomicAdd(out, contrib);
    }
    if (tid >= 64) return;

    // DP: anti-diagonal wavefront, lane u
    const int u = tid;
    const int ua = (u < U1_) ? u : U1_ - 1;
    float val = 0.0f, afin = 0.0f;

    for (int d = 1; d <= (T_ - 1) + (U1_ - 1); d++) {
        int t = d - u;
        int tb = t - 1; tb = tb < 0 ? 0 : (tb > T_ - 1 ? T_ - 1 : tb);
        int tc = t < 0 ? 0 : (t > T_ - 1 ? T_ - 1 : t);
        float blv = blp[tb * U1_ + ua];
        float elv = elp[tc * U1_ + (ua > 0 ? ua - 1 : 0)];
        float up = __shfl_up(val, 1, 64);
        bool valid = (u < U1_) && (t >= 0) && (t < T_);
        if (valid) {
            if (t == 0) {
                val = up + elv;
            } else if (u == 0) {
                val = val + blv;
            } else {
                float a1 = val + blv;
                float a2 = up + elv;
                float mx = fmaxf(a1, a2), mn = fminf(a1, a2);
                val = mx + log1pf(__expf(mn - mx));
            }
            if (t == sl - 1 && u == tl) afin = val;
        }
    }
#pragma unroll
    for (int off = 1; off < 64; off <<= 1) afin += __shfl_xor(afin, off, 64);
    if (u == 0) {
        float bfin = blp[(sl - 1) * U1_ + tl];
        atomicAdd(out, -(afin + bfin));
    }
}

// ---------------------------------------------------------------------------
extern "C" void kernel_launch(void* const* d_in, const int* in_sizes, int n_in,
                              void* d_out, int out_size, void* d_ws, size_t ws_size,
                              hipStream_t stream)
{
    const float* x           = (const float*)d_in[0];
    const float* w           = (const float*)d_in[1];
    const float* bias        = (const float*)d_in[2];
    const int*   targets     = (const int*)d_in[3];
    const int*   src_lengths = (const int*)d_in[4];
    const int*   tgt_lengths = (const int*)d_in[5];
    float* out = (float*)d_out;

    char* p = (char*)d_ws;
    uint8_t* wf8 = (uint8_t*)p;      p += (size_t)V_ * D_;                  // 2.1 MB
    float* partial_e = (float*)p;    p += (size_t)2 * M_ * sizeof(float);   // 270 KB
    float* partial_z = (float*)p;    p += (size_t)2 * M_ * sizeof(float);
    float* blank_z   = (float*)p;    p += (size_t)M_ * sizeof(float);
    float* emit_z    = (float*)p;    p += (size_t)M_ * sizeof(float);

    wconvert<<<512, 256, 0, stream>>>(w, wf8, out);
    gemm_fused<<<dim3(M_/TM, 2), 256, 0, stream>>>(x, wf8, bias, targets,
                                                   partial_e, partial_z, blank_z, emit_z);
    dp_kernel<<<B_, 256, 0, stream>>>(partial_e, partial_z, blank_z, emit_z,
                                      targets, src_lengths, tgt_lengths, out);
}